// Round 3
// baseline (2032.052 us; speedup 1.0000x reference)
//
#include <hip/hip_runtime.h>
#include <cmath>

namespace {
constexpr int B_ = 16, T_ = 512, P_ = 256, E_ = 128, NB_ = 4, K_ = 4;
constexpr int THREADS_ = 512;
constexpr int RS_ = 132;   // padded ring row stride (floats): rows shift banks by 4

__device__ __forceinline__ float rcpf(float x) { return __builtin_amdgcn_rcpf(x); }
__device__ __forceinline__ float fast_tanh(float x) {
    float a = fabsf(x);
    float t = __expf(-2.0f * a);
    float r = 1.0f - 2.0f * t * rcpf(1.0f + t);
    return copysignf(r, x);
}

// ---- cross-lane reductions on the VALU pipe (DPP + permlane), freeing the DS pipe
template<int CTRL>
__device__ __forceinline__ float dpp_addf(float v) {
    const int s = __builtin_amdgcn_update_dpp(0, __float_as_int(v), CTRL, 0xF, 0xF, true);
    return v + __int_as_float(s);
}
template<int Q>
__device__ __forceinline__ float dpp_bcast4(float v) {   // broadcast quad position Q
    const int s = __builtin_amdgcn_update_dpp(0, __float_as_int(v), Q * 0x55, 0xF, 0xF, true);
    return __int_as_float(s);
}
__device__ __forceinline__ float pl16_sum(float v) {     // v + v[lane^16]
#if __has_builtin(__builtin_amdgcn_permlane16_swap)
    const unsigned u = __float_as_uint(v);
    const auto r = __builtin_amdgcn_permlane16_swap(u, u, false, false);
    return __uint_as_float(r[0]) + __uint_as_float(r[1]);
#else
    return v + __shfl_xor(v, 16);
#endif
}
__device__ __forceinline__ float pl32_sum(float v) {     // v + v[lane^32]
#if __has_builtin(__builtin_amdgcn_permlane32_swap)
    const unsigned u = __float_as_uint(v);
    const auto r = __builtin_amdgcn_permlane32_swap(u, u, false, false);
    return __uint_as_float(r[0]) + __uint_as_float(r[1]);
#else
    return v + __shfl_xor(v, 32);
#endif
}
// sum over the 8 kq groups (lane bits 3,4,5)
__device__ __forceinline__ float redkq8(float v) {
    v = dpp_addf<0x128>(v);      // row_ror:8 == xor8 within 16-row
    v = pl16_sum(v);
    v = pl32_sum(v);
    return v;
}
// sum over lane bits 0,1,2 (the 8 pair slots): masks {1,2,7} span the 3-bit space
__device__ __forceinline__ float redpair(float v) {
    v = dpp_addf<0xB1>(v);       // quad_perm(1,0,3,2) = xor1
    v = dpp_addf<0x4E>(v);       // quad_perm(2,3,0,1) = xor2
    v = dpp_addf<0x141>(v);      // row_half_mirror   = xor7
    return v;
}
// compile-time mux of 8 values by kq (no scratch demotion)
__device__ __forceinline__ float sel8f(int kq, float w0, float w1, float w2, float w3,
                                       float w4, float w5, float w6, float w7) {
    const float a = (kq & 1) ? w1 : w0;
    const float b = (kq & 1) ? w3 : w2;
    const float c = (kq & 1) ? w5 : w4;
    const float d = (kq & 1) ? w7 : w6;
    const float e = (kq & 2) ? b : a;
    const float f = (kq & 2) ? d : c;
    return (kq & 4) ? f : e;
}
}

// R11b: DS-pipe diet (fixed permlane vector-element access). 512 thr / 8 waves
// (2 per SIMD), e-PAIR layout with 8-way k-split: lane (w,l): pair pr=8w+(l&7),
// e0=2*pr, kq=l>>3 (0..7).
//  - matvec: 16 ds_read_b128/lane (each feeds 8 FMA) from padded s4 (stride 17f4)
//  - gather/scatter: b64, one ring row per kq (+row base+4 on kq0), ring rows
//    padded to 132 floats so kq groups hit disjoint banks
//  - ALL reductions via DPP/permlane (VALU pipe): zero ds_swizzle
//  - jump-red combine: 1 ds_read_b32 + DPP tree (was 8 b128 broadcast reads)
__global__ __launch_bounds__(512, 1)
void swarm_ring_kernel(const float* __restrict__ x,            // (B,T,8)
                       const float* __restrict__ W_in,         // (8,E)
                       const float* __restrict__ b_in,         // (E)
                       const float* __restrict__ W_out,        // (E,8)
                       const float* __restrict__ b_out,        // (8)
                       const float* __restrict__ W_p,          // (E,E)
                       const float* __restrict__ b_p,          // (E)
                       const float* __restrict__ ptr_dest,     // (NB,P)
                       const float* __restrict__ jump_W,       // (NB,E)
                       const float* __restrict__ jump_b,       // (NB)
                       const float* __restrict__ ctx_strength, // (NB)
                       const float* __restrict__ phase_bias,   // (NB,E)
                       const float* __restrict__ pointer_init, // (NB,B)
                       float* __restrict__ out)                // (B,T,8)
{
    __shared__ alignas(16) float  ring[P_ * RS_];   // 132 KiB, padded rows
    __shared__ alignas(16) float4 s4[136];          // fast: s1 4-bot packs, stride 17/16
    __shared__ alignas(16) float  sbuf[2][160];     // slow: s broadcast, pad 4f/16f
    __shared__ alignas(16) float  red[32];          // per-wave jump partials
    __shared__ alignas(16) float  hist[16][132];    // ssum history ring
    __shared__ alignas(16) float  wout_s[8][132];   // 0.25 * W_out^T

    const int tid = threadIdx.x;
    const int b   = blockIdx.x;
    const int w   = tid >> 6;
    const int l   = tid & 63;
    const int s_  = l & 7;
    const int kq  = l >> 3;                         // 0..7
    const int e0  = ((w << 3) | s_) << 1;           // owned e-pair: e0, e0+1

    for (int k4 = tid; k4 < P_ * RS_ / 4; k4 += THREADS_)
        ((float4*)ring)[k4] = make_float4(0.f, 0.f, 0.f, 0.f);
    for (int idx = tid; idx < 8 * E_; idx += THREADS_) {
        const int m = idx >> 7, ee = idx & 127;
        wout_s[m][ee] = W_out[ee * 8 + m] * 0.25f;
    }

    float2 wp2[16];                                 // W_p[16*kq+kk][e0..e0+1]
    #pragma unroll
    for (int kk = 0; kk < 16; ++kk)
        wp2[kk] = *(const float2*)(W_p + (kq * 16 + kk) * E_ + e0);

    float2 wi2[8];                                  // W_in[k][e0..e0+1]
    #pragma unroll
    for (int k = 0; k < 8; ++k)
        wi2[k] = *(const float2*)(W_in + k * E_ + e0);

    const float2 bin2 = *(const float2*)(b_in + e0);
    const float2 bp2  = *(const float2*)(b_p + e0);
    const float  bout_m = b_out[tid & 7];

    float2 pb2[NB_], jw2[NB_], hid2[NB_];
    float  sigc[NB_], jb_r[NB_], ptrv[NB_];
    #pragma unroll
    for (int i = 0; i < NB_; ++i) {
        const float2 pb = *(const float2*)(phase_bias + i * E_ + e0);
        pb2[i] = make_float2(0.1f * pb.x, 0.1f * pb.y);
        jw2[i] = *(const float2*)(jump_W + i * E_ + e0);
        sigc[i] = 1.0f / (1.0f + __expf(-ctx_strength[i]));
        jb_r[i] = jump_b[i];
        hid2[i] = make_float2(0.f, 0.f);
        ptrv[i] = pointer_init[i * B_ + b];
    }

    const float* xb = x + (size_t)b * T_ * 8;
    float xt[8];
    {
        float4 a0 = ((const float4*)xb)[0], a1 = ((const float4*)xb)[1];
        xt[0]=a0.x; xt[1]=a0.y; xt[2]=a0.z; xt[3]=a0.w;
        xt[4]=a1.x; xt[5]=a1.y; xt[6]=a1.z; xt[7]=a1.w;
    }

    const float Cw1 = 0.8824969f, Cw2 = 0.60653066f, Cw3 = 0.32465247f, Cw4 = 0.13533528f;
    const float Dw1 = 0.7788008f, Dw2 = 0.36787944f, Dw3 = 0.105399225f, Dw4 = 0.018315639f;

    __syncthreads();

    for (int t = 0; t < T_; ++t) {
        // ---- geometry, softmax weights, jump-target prefetch (proven math)
        int   baseA[NB_];
        float fA[NB_], psinv[NB_], jt[NB_], wgt[NB_][9];
        #pragma unroll
        for (int i = 0; i < NB_; ++i) {
            const float p = ptrv[i];
            const int base = (int)p;
            baseA[i] = base;
            jt[i] = ptr_dest[i * P_ + base];
            const float f = p - (float)base;
            fA[i] = f;
            const float r  = __expf(0.25f * f);
            const float r2 = r * r, r3 = r2 * r, r4 = r2 * r2;
            const float ri = rcpf(r), ri2 = ri * ri, ri3 = ri2 * ri, ri4 = ri2 * ri2;
            const float p0 = Cw4*ri4, p1 = Cw3*ri3, p2 = Cw2*ri2, p3 = Cw1*ri, p4 = 1.0f,
                        p5 = Cw1*r,  p6 = Cw2*r2,  p7 = Cw3*r3,  p8 = Cw4*r4;
            const float sum = ((p0+p1)+(p2+p3)) + ((p4+p5)+(p6+p7)) + p8;
            const float inv = rcpf(sum);
            psinv[i] = inv;
            wgt[i][0]=p0*inv; wgt[i][1]=p1*inv; wgt[i][2]=p2*inv; wgt[i][3]=p3*inv;
            wgt[i][4]=p4*inv; wgt[i][5]=p5*inv; wgt[i][6]=p6*inv; wgt[i][7]=p7*inv;
            wgt[i][8]=p8*inv;
        }

        // ---- block-uniform independence test
        int ddm[NB_][NB_];
        bool overlap = false;
        #pragma unroll
        for (int j = 1; j < NB_; ++j)
            #pragma unroll
            for (int i = 0; i < j; ++i) {
                const int dd = ((baseA[j] - baseA[i] + 128) & 255) - 128;
                ddm[j][i] = dd;
                overlap = overlap || (dd >= -8 && dd <= 8);
            }

        // ---- gathers: row kq-4 per group (+row +4 on kq0), b64; reduce on VALU
        float  ws[NB_], w8[NB_];
        float2 ctxp2[NB_];
        #pragma unroll
        for (int i = 0; i < NB_; ++i) {
            ws[i] = sel8f(kq, wgt[i][0], wgt[i][1], wgt[i][2], wgt[i][3],
                              wgt[i][4], wgt[i][5], wgt[i][6], wgt[i][7]);
            w8[i] = wgt[i][8];
            const int r0 = (baseA[i] + kq - K_) & (P_ - 1);
            const float2 g0 = *(const float2*)(ring + r0 * RS_ + e0);
            float cx = ws[i] * g0.x;
            float cy = ws[i] * g0.y;
            if (kq == 0) {
                const int r2 = (baseA[i] + K_) & (P_ - 1);
                const float2 g2 = *(const float2*)(ring + r2 * RS_ + e0);
                cx = fmaf(w8[i], g2.x, cx);
                cy = fmaf(w8[i], g2.y, cy);
            }
            ctxp2[i] = make_float2(redkq8(cx), redkq8(cy));
        }

        // ---- inp = x_t @ W_in + b_in (weights in registers)
        float2 inp2 = bin2;
        #pragma unroll
        for (int k = 0; k < 8; ++k) {
            inp2.x = fmaf(xt[k], wi2[k].x, inp2.x);
            inp2.y = fmaf(xt[k], wi2[k].y, inp2.y);
        }

        float xtn[8];
        if (t + 1 < T_) {
            float4 a0 = ((const float4*)(xb + (t + 1) * 8))[0];
            float4 a1 = ((const float4*)(xb + (t + 1) * 8))[1];
            xtn[0]=a0.x; xtn[1]=a0.y; xtn[2]=a0.z; xtn[3]=a0.w;
            xtn[4]=a1.x; xtn[5]=a1.y; xtn[6]=a1.z; xtn[7]=a1.w;
        } else {
            #pragma unroll
            for (int k = 0; k < 8; ++k) xtn[k] = 0.f;
        }

        float2 sv2[NB_];

        if (!overlap) {
            // ================= FAST PATH: all 4 bots independent =================
            float2 s1v[NB_];
            #pragma unroll
            for (int j = 0; j < NB_; ++j) {
                s1v[j].x = fast_tanh(fmaf(sigc[j], ctxp2[j].x, inp2.x + pb2[j].x + hid2[j].x));
                s1v[j].y = fast_tanh(fmaf(sigc[j], ctxp2[j].y, inp2.y + pb2[j].y + hid2[j].y));
            }
            if (kq == 0) {
                const int si = 17 * w + (s_ << 1);   // e0 + (e0>>4)
                s4[si]     = make_float4(s1v[0].x, s1v[1].x, s1v[2].x, s1v[3].x);
                s4[si + 1] = make_float4(s1v[0].y, s1v[1].y, s1v[2].y, s1v[3].y);
            }
            __syncthreads();                        // ONE barrier for all 4 broadcasts

            float2 ab0 = make_float2(0.f, 0.f), ab1 = ab0, ab2 = ab0, ab3 = ab0;
            const float4* sp = s4 + kq * 17;        // padded: idx(16kq+kk)=17kq+kk
            #pragma unroll
            for (int kk = 0; kk < 16; ++kk) {
                const float4 sq = sp[kk];
                const float2 w2 = wp2[kk];
                ab0.x = fmaf(sq.x, w2.x, ab0.x); ab0.y = fmaf(sq.x, w2.y, ab0.y);
                ab1.x = fmaf(sq.y, w2.x, ab1.x); ab1.y = fmaf(sq.y, w2.y, ab1.y);
                ab2.x = fmaf(sq.z, w2.x, ab2.x); ab2.y = fmaf(sq.z, w2.y, ab2.y);
                ab3.x = fmaf(sq.w, w2.x, ab3.x); ab3.y = fmaf(sq.w, w2.y, ab3.y);
            }
            sv2[0] = make_float2(fast_tanh(redkq8(ab0.x) + bp2.x), fast_tanh(redkq8(ab0.y) + bp2.y));
            sv2[1] = make_float2(fast_tanh(redkq8(ab1.x) + bp2.x), fast_tanh(redkq8(ab1.y) + bp2.y));
            sv2[2] = make_float2(fast_tanh(redkq8(ab2.x) + bp2.x), fast_tanh(redkq8(ab2.y) + bp2.y));
            sv2[3] = make_float2(fast_tanh(redkq8(ab3.x) + bp2.x), fast_tanh(redkq8(ab3.y) + bp2.y));
            #pragma unroll
            for (int j = 0; j < NB_; ++j) hid2[j] = sv2[j];

            // disjoint b64 scatters: lane owns row kq-4 (+row +4 on kq0)
            #pragma unroll
            for (int j = 0; j < NB_; ++j) {
                const float2 s = sv2[j];
                const int r0 = (baseA[j] + kq - K_) & (P_ - 1);
                float2* q0 = (float2*)(ring + r0 * RS_ + e0);
                float2 v0 = *q0;
                v0.x = fmaf(ws[j], s.x, v0.x); v0.y = fmaf(ws[j], s.y, v0.y);
                *q0 = v0;
                if (kq == 0) {
                    const int r2 = (baseA[j] + K_) & (P_ - 1);
                    float2* q2 = (float2*)(ring + r2 * RS_ + e0);
                    float2 v2 = *q2;
                    v2.x = fmaf(w8[j], s.x, v2.x); v2.y = fmaf(w8[j], s.y, v2.y);
                    *q2 = v2;
                }
            }
        } else {
            // ================= SLOW PATH: serial chain with coef corrections =====
            float coefm[NB_][NB_];
            #pragma unroll
            for (int j = 1; j < NB_; ++j) {
                #pragma unroll
                for (int i = 0; i < j; ++i) {
                    const int dd = ddm[j][i];
                    float c = 0.f;
                    if (dd >= -8 && dd <= 8) {
                        const float A = (float)dd - fA[i];
                        const float s  = __expf(-0.25f * (A - fA[j]));
                        const float G  = __expf(0.125f * (fA[i] * fA[i] - A * A));
                        const float s2p = s * s, s3p = s2p * s, s4p = s2p * s2p;
                        const float si = rcpf(s), si2 = si * si, si3 = si2 * si, si4 = si2 * si2;
                        float acc = 0.f;
                        acc += (dd >= 0)              ? Dw4 * si4 : 0.f;
                        acc += (dd >= -1 && dd <= 7)  ? Dw3 * si3 : 0.f;
                        acc += (dd >= -2 && dd <= 6)  ? Dw2 * si2 : 0.f;
                        acc += (dd >= -3 && dd <= 5)  ? Dw1 * si  : 0.f;
                        acc += (dd >= -4 && dd <= 4)  ? 1.0f      : 0.f;
                        acc += (dd >= -5 && dd <= 3)  ? Dw1 * s   : 0.f;
                        acc += (dd >= -6 && dd <= 2)  ? Dw2 * s2p : 0.f;
                        acc += (dd >= -7 && dd <= 1)  ? Dw3 * s3p : 0.f;
                        acc += (dd <= 0)              ? Dw4 * s4p : 0.f;
                        c = psinv[i] * psinv[j] * G * acc;
                    }
                    coefm[j][i] = c;
                }
            }

            #pragma unroll
            for (int j = 0; j < NB_; ++j) {
                float2 ctx = ctxp2[j];
                #pragma unroll
                for (int i = 0; i < j; ++i) {
                    ctx.x = fmaf(coefm[j][i], sv2[i].x, ctx.x);
                    ctx.y = fmaf(coefm[j][i], sv2[i].y, ctx.y);
                }
                float2 s1;
                s1.x = fast_tanh(fmaf(sigc[j], ctx.x, inp2.x + pb2[j].x + hid2[j].x));
                s1.y = fast_tanh(fmaf(sigc[j], ctx.y, inp2.y + pb2[j].y + hid2[j].y));
                if (kq == 0) {
                    const int pf = 20 * w + (s_ << 1);   // e0 + 4*(e0>>4)
                    *(float2*)(&sbuf[j & 1][pf]) = s1;
                }
                __syncthreads();                    // s broadcast ready

                const float4* sp4 = (const float4*)(&sbuf[j & 1][0]);
                float ax = 0.f, ay = 0.f;
                #pragma unroll
                for (int m = 0; m < 4; ++m) {
                    const float4 sq = sp4[5 * kq + m];   // padded: fidx(4kq+m)=5kq+m
                    const float2 wa = wp2[4*m+0], wb = wp2[4*m+1];
                    const float2 wc = wp2[4*m+2], wd = wp2[4*m+3];
                    ax = fmaf(sq.x, wa.x, ax); ay = fmaf(sq.x, wa.y, ay);
                    ax = fmaf(sq.y, wb.x, ax); ay = fmaf(sq.y, wb.y, ay);
                    ax = fmaf(sq.z, wc.x, ax); ay = fmaf(sq.z, wc.y, ay);
                    ax = fmaf(sq.w, wd.x, ax); ay = fmaf(sq.w, wd.y, ay);
                }
                float2 s2;
                s2.x = fast_tanh(redkq8(ax) + bp2.x);
                s2.y = fast_tanh(redkq8(ay) + bp2.y);
                sv2[j] = s2; hid2[j] = s2;

                const int r0 = (baseA[j] + kq - K_) & (P_ - 1);
                float2* q0 = (float2*)(ring + r0 * RS_ + e0);
                float2 v0 = *q0;
                v0.x = fmaf(ws[j], s2.x, v0.x); v0.y = fmaf(ws[j], s2.y, v0.y);
                *q0 = v0;
                if (kq == 0) {
                    const int r2 = (baseA[j] + K_) & (P_ - 1);
                    float2* q2 = (float2*)(ring + r2 * RS_ + e0);
                    float2 v2 = *q2;
                    v2.x = fmaf(w8[j], s2.x, v2.x); v2.y = fmaf(w8[j], s2.y, v2.y);
                    *q2 = v2;
                }
            }
        }

        // ---- jump dots: per-lane pair dot, reduce the 8 pair slots on VALU
        {
            float vj0 = fmaf(sv2[0].y, jw2[0].y, sv2[0].x * jw2[0].x);
            float vj1 = fmaf(sv2[1].y, jw2[1].y, sv2[1].x * jw2[1].x);
            float vj2 = fmaf(sv2[2].y, jw2[2].y, sv2[2].x * jw2[2].x);
            float vj3 = fmaf(sv2[3].y, jw2[3].y, sv2[3].x * jw2[3].x);
            vj0 = redpair(vj0); vj1 = redpair(vj1); vj2 = redpair(vj2); vj3 = redpair(vj3);
            if (l == 0)
                ((float4*)red)[w] = make_float4(vj0, vj1, vj2, vj3);
        }

        // ---- ssum -> history ring (kq0 lanes, b64)
        {
            float2 ssum2;
            ssum2.x = (sv2[0].x + sv2[1].x) + (sv2[2].x + sv2[3].x);
            ssum2.y = (sv2[0].y + sv2[1].y) + (sv2[2].y + sv2[3].y);
            if (kq == 0) *(float2*)(&hist[t & 15][e0]) = ssum2;
        }

        __syncthreads();                            // scatters + red + hist visible

        // ---- zz combine: 1 b32 read + DPP tree (lane l holds red[4w'+bot])
        {
            float rv = red[l & 31];
            rv = dpp_addf<0x124>(rv);               // row_ror:4 -> + same-bot, w'+1
            rv = dpp_addf<0x128>(rv);               // row_ror:8 -> all w' in 16-row
            rv = pl16_sum(rv);                      // + other 16-row
            const float zz0 = dpp_bcast4<0>(rv) + jb_r[0];
            const float zz1 = dpp_bcast4<1>(rv) + jb_r[1];
            const float zz2 = dpp_bcast4<2>(rv) + jb_r[2];
            const float zz3 = dpp_bcast4<3>(rv) + jb_r[3];
            const float zz[4] = { zz0, zz1, zz2, zz3 };
            #pragma unroll
            for (int i = 0; i < NB_; ++i) {
                float np;
                if (zz[i] > 0.0f) np = jt[i];
                else { np = ptrv[i] + 1.0f; if (np >= 256.0f) np -= 256.0f; }
                ptrv[i] = np;
            }
        }

        // ---- every 8th step: 64 threads compute the deferred out dots
        if ((t & 7) == 7 && tid < 64) {
            const int tt = tid >> 3;
            const int m  = tid & 7;
            const float* hrow = hist[(t - 7 + tt) & 15];
            const float* wrow = wout_s[m];
            float acc = 0.f;
            #pragma unroll
            for (int q = 0; q < 32; ++q) {
                const float4 h4 = ((const float4*)hrow)[q];
                const float4 w4 = ((const float4*)wrow)[q];
                acc += ((h4.x * w4.x + h4.y * w4.y) + (h4.z * w4.z + h4.w * w4.w));
            }
            out[((size_t)b * T_ + (t - 7 + tt)) * 8 + m] = acc + bout_m;
        }

        #pragma unroll
        for (int k = 0; k < 8; ++k) xt[k] = xtn[k];
    }
}

extern "C" void kernel_launch(void* const* d_in, const int* in_sizes, int n_in,
                              void* d_out, int out_size, void* d_ws, size_t ws_size,
                              hipStream_t stream) {
    (void)in_sizes; (void)n_in; (void)out_size; (void)d_ws; (void)ws_size;
    swarm_ring_kernel<<<dim3(B_), dim3(THREADS_), 0, stream>>>(
        (const float*)d_in[0],  (const float*)d_in[1],  (const float*)d_in[2],
        (const float*)d_in[3],  (const float*)d_in[4],  (const float*)d_in[5],
        (const float*)d_in[6],  (const float*)d_in[7],  (const float*)d_in[8],
        (const float*)d_in[9],  (const float*)d_in[10], (const float*)d_in[11],
        (const float*)d_in[12], (float*)d_out);
}